// Round 1
// 113.523 us; speedup vs baseline: 1.0245x; 1.0245x over previous
//
#include <hip/hip_runtime.h>
#include <hip/hip_bf16.h>

// KAN harmonic-basis GEMM, v4.
// out[b,h] = sum_{d,f} basis(x[b,d])[f] * W[d,f,h] + sum_d b[d,h]
//
// f=0 + bias -> fp32 partials c_part[8][256], summed in GEMM epilogue.
// f=1..10    -> bf16 MFMA GEMM, M=16384, N=256, K=2560.
//   A generated on the fly (sincos once + Chebyshev harmonic recurrence),
//   written to LDS in MFMA-fragment-linear layout (conflict-free b128 r/w).
//   B = Wfrag (d_ws), fragment-linear in global; loads are 1KB-contiguous
//   per wave.
// v4 changes (latency-bound fix: MfmaUtil/VALUBusy were ~14%, occupancy 19%):
//   - B prefetch deepened from 1-step to a 5-deep rolling pipeline over the
//     flattened k index kt = dtile*10+hs (depth 5 divides 10 -> all register
//     buffer indices compile-time). Pipeline crosses dtile boundaries, so
//     next dtile's first 5 B k-steps are in flight during A-gen.
//   - A fragment reads from LDS deepened to a 3-deep rolling pipeline.
//   - As double-buffered (2 x 40,960 B = 81,920 B; 2 blocks/CU exactly at
//     160 KiB) -> ONE __syncthreads per dtile instead of two.

#define BDIM 16384
#define DDIM 256
#define HOUT 256
#define KTOT 2560
#define NKT  80
#define BM 64
#define BN 128

typedef __bf16 bf16x8 __attribute__((ext_vector_type(8)));
typedef float floatx4 __attribute__((ext_vector_type(4)));

__device__ __forceinline__ unsigned short f2bf(float f) {
    unsigned int u = __float_as_uint(f);
    return (unsigned short)((u + 0x7FFFu + ((u >> 16) & 1u)) >> 16);
}

__device__ __forceinline__ unsigned int pkbf(float a, float b) {
    __hip_bfloat162 r = __float22bfloat162_rn(make_float2(a, b));
    return *reinterpret_cast<unsigned int*>(&r);
}

// grid 88 x 256 threads.
// blocks [0,80): kt = bid; Wfrag[kt][n][dd] = bf16(W[dtile*32+dd][kt%10+1][n])
// blocks [80,88): p = bid-80; c_part[p][h] = sum_{d in p*32..+32} W[d][0][h]+b[d][h]
__global__ void prep_kernel(const float* __restrict__ W, const float* __restrict__ bias,
                            unsigned short* __restrict__ Wfrag, float* __restrict__ c_part) {
    const int bid = blockIdx.x;
    const int t = threadIdx.x;
    if (bid < NKT) {
        const int kt = bid;
        const int dtile = kt / 10;
        const int f = kt - dtile * 10 + 1;
        const float* wsrc = W + ((size_t)(dtile * 32) * 11 + f) * 256 + t;
        union { unsigned short s[32]; int4 v[4]; } buf;
#pragma unroll
        for (int dd = 0; dd < 32; ++dd)
            buf.s[dd] = f2bf(wsrc[(size_t)dd * 11 * 256]);
        int4* dst = (int4*)(Wfrag + ((size_t)kt * 256 + t) * 32);
#pragma unroll
        for (int v = 0; v < 4; ++v) dst[v] = buf.v[v];
    } else {
        const int p = bid - NKT;
        float acc = 0.f;
#pragma unroll
        for (int dd = 0; dd < 32; ++dd) {
            const int d = p * 32 + dd;
            acc += W[(size_t)(d * 11) * 256 + t] + bias[(size_t)d * 256 + t];
        }
        c_part[p * 256 + t] = acc;
    }
}

// As layout: tile (hs, itile): base short offset (hs*4+itile)*512, lane slot lane*8.
// A wave's afrag read = 64 lanes x 16 B contiguous (1 KB). Gen writes are
// 16-lane-contiguous 256 B chunks. Both conflict-free.
__global__ __launch_bounds__(256, 2)
void kan_gemm(const float* __restrict__ x, const unsigned short* __restrict__ Wfrag,
              const float* __restrict__ c_part, float* __restrict__ out) {
    __shared__ unsigned short As[2][10 * 4 * 512];   // 2 x 40,960 B -> 2 blocks/CU

    const int t = threadIdx.x;
    const int m0 = blockIdx.x * BM;
    const int h0 = blockIdx.y * BN;

    const int lane = t & 63;
    const int wave = t >> 6;
    const int wr = wave >> 1;        // row half (32 rows)
    const int wc = wave & 1;         // col half (64 cols)
    const int l15 = lane & 15;
    const int koff = lane >> 4;

    // A-gen: row = lane, d-chunk of 8 = wave
    const int m_a = lane;
    const int q = wave;
    const int it_w = m_a >> 4;                    // which i-tile this thread's row is in
    const int slot = (m_a & 15) + 16 * q;         // lane slot within fragment tile

    floatx4 acc[2][4];
#pragma unroll
    for (int i = 0; i < 2; ++i)
#pragma unroll
        for (int j = 0; j < 4; ++j)
            acc[i][j] = (floatx4){0.f, 0.f, 0.f, 0.f};

    const float* xrow = x + (size_t)(m0 + m_a) * DDIM;
    const unsigned short* bbase = Wfrag + (size_t)(h0 + wc * 64 + l15) * 32 + koff * 8;

    float4 xa = *(const float4*)(xrow + q * 8);
    float4 xb = *(const float4*)(xrow + q * 8 + 4);

    // ---- B pipeline prologue: flat kt = 0..4 in flight before first A-gen ----
    bf16x8 bf[5][4];
#pragma unroll
    for (int p = 0; p < 5; ++p)
#pragma unroll
        for (int j = 0; j < 4; ++j)
            bf[p][j] = *(const bf16x8*)(bbase + (size_t)p * 8192 + j * 512);

    for (int dtile = 0; dtile < 8; ++dtile) {
        unsigned short* asb = &As[dtile & 1][0];

        // ---- A-gen: sincos once, Chebyshev for harmonics 2..5 ----
        float xv[8] = {xa.x, xa.y, xa.z, xa.w, xb.x, xb.y, xb.z, xb.w};
        float sc[8], cc[8], sp[8], cp[8], t2c[8];
#pragma unroll
        for (int j = 0; j < 8; ++j) {
            __sincosf(xv[j], &sc[j], &cc[j]);
            t2c[j] = cc[j] + cc[j];
            sp[j] = 0.f;
            cp[j] = 1.f;
        }
#pragma unroll
        for (int k = 1; k <= 5; ++k) {
            union { unsigned int u[4]; int4 v; } vs, vc;
#pragma unroll
            for (int p = 0; p < 4; ++p) {
                vs.u[p] = pkbf(sc[2 * p], sc[2 * p + 1]);
                vc.u[p] = pkbf(cc[2 * p], cc[2 * p + 1]);
            }
            *(int4*)(&asb[((2 * k - 2) * 4 + it_w) * 512 + slot * 8]) = vs.v;
            *(int4*)(&asb[((2 * k - 1) * 4 + it_w) * 512 + slot * 8]) = vc.v;
            if (k < 5) {
#pragma unroll
                for (int j = 0; j < 8; ++j) {
                    const float ns = t2c[j] * sc[j] - sp[j];
                    const float nc = t2c[j] * cc[j] - cp[j];
                    sp[j] = sc[j]; cp[j] = cc[j];
                    sc[j] = ns;   cc[j] = nc;
                }
            }
        }
        __syncthreads();   // one barrier per dtile (As double-buffered)

        // prefetch next d-tile's x during MFMA phase
        if (dtile < 7) {
            xa = *(const float4*)(xrow + (dtile + 1) * 32 + q * 8);
            xb = *(const float4*)(xrow + (dtile + 1) * 32 + q * 8 + 4);
        }

        // ---- A pipeline prologue: hs = 0..2 ----
        bf16x8 af[3][2];
#pragma unroll
        for (int p = 0; p < 3; ++p)
#pragma unroll
            for (int i = 0; i < 2; ++i)
                af[p][i] = *(const bf16x8*)(&asb[(p * 4 + wr * 2 + i) * 512 + lane * 8]);

        // ---- MFMA loop: consume (hs), then refill slots for hs+5 (B) / hs+3 (A) ----
#pragma unroll
        for (int hs = 0; hs < 10; ++hs) {
#pragma unroll
            for (int i = 0; i < 2; ++i)
#pragma unroll
                for (int j = 0; j < 4; ++j)
                    acc[i][j] = __builtin_amdgcn_mfma_f32_16x16x32_bf16(af[hs % 3][i], bf[hs % 5][j], acc[i][j], 0, 0, 0);

            // B refill: flat kt + 5, clamped at tail (redundant in-bounds loads)
            {
                int ktp = dtile * 10 + hs + 5;
                if (ktp > 79) ktp = 79;
#pragma unroll
                for (int j = 0; j < 4; ++j)
                    bf[hs % 5][j] = *(const bf16x8*)(bbase + (size_t)ktp * 8192 + j * 512);
            }
            // A refill: hs + 3 within this dtile
            if (hs < 7) {
#pragma unroll
                for (int i = 0; i < 2; ++i)
                    af[hs % 3][i] = *(const bf16x8*)(&asb[((hs + 3) * 4 + wr * 2 + i) * 512 + lane * 8]);
            }
        }
        // no second barrier: next dtile writes the other As buffer
    }

    // ---- epilogue: C/D layout col=lane&15, row=(lane>>4)*4+reg ----
    float cj[4];
#pragma unroll
    for (int j = 0; j < 4; ++j) {
        const int col = h0 + wc * 64 + j * 16 + l15;
        float s = 0.f;
#pragma unroll
        for (int p = 0; p < 8; ++p) s += c_part[p * 256 + col];
        cj[j] = s;
    }
#pragma unroll
    for (int i = 0; i < 2; ++i) {
        const int row0 = m0 + wr * 32 + i * 16 + koff * 4;
#pragma unroll
        for (int j = 0; j < 4; ++j) {
            const int col = h0 + wc * 64 + j * 16 + l15;
#pragma unroll
            for (int r = 0; r < 4; ++r)
                out[(size_t)(row0 + r) * HOUT + col] = acc[i][j][r] + cj[j];
        }
    }
}

extern "C" void kernel_launch(void* const* d_in, const int* in_sizes, int n_in,
                              void* d_out, int out_size, void* d_ws, size_t ws_size,
                              hipStream_t stream) {
    const float* x = (const float*)d_in[0];
    const float* W = (const float*)d_in[1];
    const float* b = (const float*)d_in[2];
    float* out = (float*)d_out;

    unsigned short* Wfrag = (unsigned short*)d_ws;                      // 1,310,720 B
    float* c_part = (float*)((char*)d_ws + (size_t)NKT * 256 * 32 * 2); // 8 KB

    prep_kernel<<<NKT + 8, 256, 0, stream>>>(W, b, Wfrag, c_part);
    kan_gemm<<<dim3(BDIM / BM, HOUT / BN), 256, 0, stream>>>(x, Wfrag, c_part, out);
}